// Round 2
// baseline (636.313 us; speedup 1.0000x reference)
//
#include <hip/hip_runtime.h>

#define BB 32
#define SS 4096
#define DD 1024
#define HH 256

// K1: direct DFT, first 16 bins, both channels. 1024 blocks x 64 threads,
// one wave per (b, channel, bin).
__global__ void k_dft(const float* __restrict__ pat, float* __restrict__ freq) {
    int blk = blockIdx.x;            // 0..1023
    int k = blk & 15;
    int c = (blk >> 4) & 1;
    int b = blk >> 5;
    int lane = threadIdx.x;          // 0..63
    const float w = 6.28318530717958647692f / 4096.0f;
    float re = 0.f, im = 0.f;
    for (int t = lane; t < SS; t += 64) {
        float x = pat[(b * SS + t) * 2 + c];
        int m = (k * t) & 4095;      // arg reduction: period 4096
        float ang = w * (float)m;
        re += x * __cosf(ang);
        im += x * __sinf(ang);       // sign irrelevant for magnitude
    }
    for (int off = 32; off > 0; off >>= 1) {
        re += __shfl_down(re, off);
        im += __shfl_down(im, off);
    }
    if (lane == 0) freq[b * 32 + c * 16 + k] = sqrtf(re * re + im * im);
}

// K2: fWf[b][h] = bf[h] + sum_j freq[b][j] * Wf[h][j].  32 blocks x 256.
__global__ void k_fwf(const float* __restrict__ freq, const float* __restrict__ Wf,
                      const float* __restrict__ bfv, float* __restrict__ fWf) {
    int b = blockIdx.x;
    int h = threadIdx.x;
    float acc = bfv[h];
    for (int j = 0; j < 32; ++j)
        acc += freq[b * 32 + j] * Wf[h * 32 + j];
    fWf[b * HH + h] = acc;
}

// K3: fold weights: Mp/Mv/Ma [1024][2] (SoA in coef[6][1024]) and
// base[d] = bo[d] + bp@WoP[d] + bv@WoV[d] + ba@WoA[d].  4 blocks x 256.
__global__ void k_coef(const float* __restrict__ Wp, const float* __restrict__ Wv,
                       const float* __restrict__ Wa, const float* __restrict__ bp,
                       const float* __restrict__ bv, const float* __restrict__ ba,
                       const float* __restrict__ Wo, const float* __restrict__ bo,
                       float* __restrict__ coef, float* __restrict__ base) {
    int d = blockIdx.x * blockDim.x + threadIdx.x;  // 0..1023
    const float* wo = Wo + (size_t)d * DD;
    float mp0 = 0, mp1 = 0, mv0 = 0, mv1 = 0, ma0 = 0, ma1 = 0;
    float bs = bo[d];
    for (int h = 0; h < HH; ++h) {
        float w0 = wo[h];
        float w1 = wo[256 + h];
        float w2 = wo[512 + h];
        mp0 += w0 * Wp[h * 2];  mp1 += w0 * Wp[h * 2 + 1];
        mv0 += w1 * Wv[h * 2];  mv1 += w1 * Wv[h * 2 + 1];
        ma0 += w2 * Wa[h * 2];  ma1 += w2 * Wa[h * 2 + 1];
        bs  += w0 * bp[h] + w1 * bv[h] + w2 * ba[h];
    }
    coef[0 * DD + d] = mp0; coef[1 * DD + d] = mp1;
    coef[2 * DD + d] = mv0; coef[3 * DD + d] = mv1;
    coef[4 * DD + d] = ma0; coef[5 * DD + d] = ma1;
    base[d] = bs;
}

// K4: cb[b][d] = base[d] + sum_h Wo[d][768+h] * fWf[b][h].  128 blocks x 256.
__global__ void k_cb(const float* __restrict__ Wo, const float* __restrict__ fWf,
                     const float* __restrict__ base, float* __restrict__ cb) {
    int idx = blockIdx.x * blockDim.x + threadIdx.x;  // 0..32767
    int b = idx >> 10;
    int d = idx & 1023;
    const float* wo = Wo + (size_t)d * DD + 768;
    const float* fw = fWf + b * HH;
    float acc = base[d];
    for (int h = 0; h < HH; ++h) acc += wo[h] * fw[h];
    cb[idx] = acc;
}

// K5: streaming epilogue.  out[b,s,d] = p.Mp[d] + v.Mv[d] + a.Ma[d] + cb[b,d].
// 256 threads/block, each thread owns 4 consecutive d's; block writes 128 rows.
// Grid 1024 blocks (32 per batch).
__global__ __launch_bounds__(256) void k_main(
        const float2* __restrict__ pat2, // pattern as float2 per (b,s)
        const float* __restrict__ coef,  // [6][1024]
        const float* __restrict__ cb,    // [32][1024]
        float* __restrict__ out) {
    int t = threadIdx.x;
    int d0 = t * 4;
    const int blkPerB = SS / 128;       // 32
    int b = blockIdx.x / blkPerB;
    int s0 = (blockIdx.x % blkPerB) * 128;

    float mp0[4], mp1[4], mv0[4], mv1[4], ma0[4], ma1[4], c4[4];
#pragma unroll
    for (int j = 0; j < 4; ++j) {
        mp0[j] = coef[0 * DD + d0 + j];
        mp1[j] = coef[1 * DD + d0 + j];
        mv0[j] = coef[2 * DD + d0 + j];
        mv1[j] = coef[3 * DD + d0 + j];
        ma0[j] = coef[4 * DD + d0 + j];
        ma1[j] = coef[5 * DD + d0 + j];
        c4[j]  = cb[b * DD + d0 + j];
    }
    const float2* prow = pat2 + (size_t)b * SS;
    for (int i = 0; i < 128; ++i) {
        int s = s0 + i;
        float2 P  = prow[s];
        float2 Q  = prow[s >= 1 ? s - 1 : 0];
        float2 R  = prow[s >= 2 ? s - 2 : 0];
        float v0, v1, a0, a1;
        if (s >= 2) {
            v0 = P.x - Q.x; v1 = P.y - Q.y;
            a0 = v0 - (Q.x - R.x); a1 = v1 - (Q.y - R.y);
        } else if (s == 1) {
            v0 = P.x - Q.x; v1 = P.y - Q.y; a0 = v0; a1 = v1;
        } else {
            v0 = 0.f; v1 = 0.f; a0 = 0.f; a1 = 0.f;
        }
        float4 o;
        o.x = c4[0] + P.x * mp0[0] + P.y * mp1[0] + v0 * mv0[0] + v1 * mv1[0] + a0 * ma0[0] + a1 * ma1[0];
        o.y = c4[1] + P.x * mp0[1] + P.y * mp1[1] + v0 * mv0[1] + v1 * mv1[1] + a0 * ma0[1] + a1 * ma1[1];
        o.z = c4[2] + P.x * mp0[2] + P.y * mp1[2] + v0 * mv0[2] + v1 * mv1[2] + a0 * ma0[2] + a1 * ma1[2];
        o.w = c4[3] + P.x * mp0[3] + P.y * mp1[3] + v0 * mv0[3] + v1 * mv1[3] + a0 * ma0[3] + a1 * ma1[3];
        *(float4*)(out + (((size_t)(b * SS + s)) << 10) + d0) = o;
    }
}

extern "C" void kernel_launch(void* const* d_in, const int* in_sizes, int n_in,
                              void* d_out, int out_size, void* d_ws, size_t ws_size,
                              hipStream_t stream) {
    const float* pattern = (const float*)d_in[0];
    const float* Wp = (const float*)d_in[1];
    const float* bp = (const float*)d_in[2];
    const float* Wv = (const float*)d_in[3];
    const float* bv = (const float*)d_in[4];
    const float* Wa = (const float*)d_in[5];
    const float* ba = (const float*)d_in[6];
    const float* Wf = (const float*)d_in[7];
    const float* bfv = (const float*)d_in[8];
    const float* Wo = (const float*)d_in[9];
    const float* bo = (const float*)d_in[10];

    float* ws   = (float*)d_ws;
    float* freq = ws;            // 1024 floats
    float* fWf  = ws + 1024;     // 8192 floats
    float* coef = ws + 9216;     // 6144 floats
    float* base = ws + 15360;    // 1024 floats
    float* cb   = ws + 16384;    // 32768 floats   (total 192 KiB)
    float* out  = (float*)d_out;

    k_dft <<<1024, 64, 0, stream>>>(pattern, freq);
    k_fwf <<<32, 256, 0, stream>>>(freq, Wf, bfv, fWf);
    k_coef<<<4, 256, 0, stream>>>(Wp, Wv, Wa, bp, bv, ba, Wo, bo, coef, base);
    k_cb  <<<128, 256, 0, stream>>>(Wo, fWf, base, cb);
    k_main<<<1024, 256, 0, stream>>>((const float2*)pattern, coef, cb, out);
}